// Round 1
// baseline (2915.201 us; speedup 1.0000x reference)
//
#include <hip/hip_runtime.h>
#include <stdint.h>

typedef __attribute__((ext_vector_type(8))) short short8;
typedef __attribute__((ext_vector_type(4))) float f32x4;

// Problem constants (fixed by the reference): B=2048 traj, T=32, I=H=1024
#define NTRAJ 2048
#define TSTEP 32
#define HDIM  1024
#define KCAT  2048   // I + H
#define NGATE 4096   // 4*H

__device__ __forceinline__ unsigned short f2bf(float f) {
  union { float f; unsigned int u; } v; v.f = f;
  unsigned int u = v.u + 0x7FFFu + ((v.u >> 16) & 1u);   // RNE
  return (unsigned short)(u >> 16);
}
__device__ __forceinline__ float sigmoidf_(float x) {
  return 1.0f / (1.0f + __expf(-x));
}
__device__ __forceinline__ float tanhf_(float x) {
  return 1.0f - 2.0f / (__expf(2.0f * x) + 1.0f);
}

// ---------------- prep kernels ----------------

// fp32 -> bf16, 4 elems/thread (used for head_output -> X)
__global__ void cvt_bf16_kernel(const float* __restrict__ src,
                                unsigned short* __restrict__ dst, int n4) {
  int i = blockIdx.x * blockDim.x + threadIdx.x;
  if (i >= n4) return;
  float4 v = ((const float4*)src)[i];
  ushort4 o;
  o.x = f2bf(v.x); o.y = f2bf(v.y); o.z = f2bf(v.z); o.w = f2bf(v.w);
  ((ushort4*)dst)[i] = o;
}

// Build Wcat[4096][2048] bf16 = [w_ih | w_hh] (both stored row-major [4096][1024])
__global__ void wcat_kernel(const float* __restrict__ wih,
                            const float* __restrict__ whh,
                            unsigned short* __restrict__ wcat) {
  int i = blockIdx.x * blockDim.x + threadIdx.x;   // float4 index, 2,097,152 total
  int e = i * 4;
  int row = e >> 11;           // /2048
  int col = e & 2047;
  const float* src = (col < 1024) ? (wih + (size_t)row * 1024 + col)
                                  : (whh + (size_t)row * 1024 + (col - 1024));
  float4 v = *(const float4*)src;
  ushort4 o;
  o.x = f2bf(v.x); o.y = f2bf(v.y); o.z = f2bf(v.z); o.w = f2bf(v.w);
  ((ushort4*)wcat)[i] = o;
}

// h0 (bf16), c0 (fp32), bias = b_ih + b_hh
__global__ void state_prep(const float* __restrict__ rnn,
                           const float* __restrict__ bih,
                           const float* __restrict__ bhh,
                           unsigned short* __restrict__ h0,
                           float* __restrict__ c0,
                           float* __restrict__ bias) {
  int i = blockIdx.x * blockDim.x + threadIdx.x;   // 0..2097151
  int b = i >> 10, j = i & 1023;
  float hv = rnn[(size_t)b * 2048 + j];
  float cv = rnn[(size_t)b * 2048 + 1024 + j];
  h0[i] = f2bf(hv);
  c0[i] = cv;
  if (i < 4096) bias[i] = bih[i] + bhh[i];
}

// ---------------- fused recurrent step ----------------
// gates = [x_t | h] @ Wcat^T + bias ; LSTM cell update fused in epilogue.
// Block: 256 thr (4 waves). Wave g computes gate g's 64x64 tile.
// Grid: (2048/64, 1024/64) = (32, 16) = 512 blocks = 2/CU (64KB LDS cap).
__global__ __launch_bounds__(256, 2)
void lstm_step(const unsigned short* __restrict__ X,     // [65536][1024] bf16
               const unsigned short* __restrict__ Wcat,  // [4096][2048] bf16
               const float* __restrict__ bias,           // [4096]
               const float* __restrict__ dones,          // [65536]
               const unsigned short* __restrict__ h_in,  // [2048][1024] bf16
               unsigned short* __restrict__ h_out,       // [2048][1024] bf16
               float* __restrict__ cbuf,                 // [2048][1024] fp32
               float* __restrict__ out,                  // x_out [65536][1024]
               float* __restrict__ rnn_out,              // [2048][2048]
               int t) {
  __shared__ union __align__(16) ShMem {
    struct { unsigned short A[64 * 32]; unsigned short Bt[4 * 64 * 32]; } st; // 20KB
    float gates[4][64 * 64];                                                  // 64KB
  } sh;

  const int tid  = threadIdx.x;
  const int wave = tid >> 6;
  const int lane = tid & 63;
  const int l16  = lane & 15;
  const int quad = lane >> 4;
  const int bBase = blockIdx.x * 64;   // batch rows
  const int n0    = blockIdx.y * 64;   // cols within one gate (0..1023)

  // accumulators init with bias (C layout: col = lane&15, same col for all 4 regs)
  f32x4 acc[4][4];
#pragma unroll
  for (int nt = 0; nt < 4; ++nt) {
    float bv = bias[wave * 1024 + n0 + nt * 16 + l16];
    f32x4 in4 = {bv, bv, bv, bv};
#pragma unroll
    for (int mt = 0; mt < 4; ++mt) acc[mt][nt] = in4;
  }

  const int ra = tid >> 2;          // A staging row (0..63)
  const int ca = (tid & 3) * 8;     // A staging col chunk

  for (int kk = 0; kk < 64; ++kk) {
    const int k0 = kk * 32;
    // stage A tile 64x32 (bf16): k<1024 -> X row (b*32+t), else h_in
    const unsigned short* asrc;
    if (k0 < 1024)
      asrc = X + ((size_t)(bBase + ra) * 32 + t) * 1024 + k0 + ca;
    else
      asrc = h_in + (size_t)(bBase + ra) * 1024 + (k0 - 1024) + ca;
    *(uint4*)&sh.st.A[ra * 32 + ca] = *(const uint4*)asrc;
    // stage B tiles: 4 gates x 64 rows x 32 cols
#pragma unroll
    for (int q = 0; q < 4; ++q) {
      int e = (q * 256 + tid) * 8;         // linear bf16 element in Bt region
      int g = e >> 11;                     // /(64*32)
      int rem = e & 2047;
      int rb = rem >> 5, cb = rem & 31;
      const unsigned short* bsrc =
          Wcat + (size_t)(g * 1024 + n0 + rb) * 2048 + k0 + cb;
      *(uint4*)&sh.st.Bt[e] = *(const uint4*)bsrc;
    }
    __syncthreads();

    short8 fa[4], fb[4];
#pragma unroll
    for (int mt = 0; mt < 4; ++mt)
      fa[mt] = *(const short8*)&sh.st.A[(mt * 16 + l16) * 32 + quad * 8];
#pragma unroll
    for (int nt = 0; nt < 4; ++nt)
      fb[nt] = *(const short8*)&sh.st.Bt[(wave * 64 + nt * 16 + l16) * 32 + quad * 8];
#pragma unroll
    for (int mt = 0; mt < 4; ++mt)
#pragma unroll
      for (int nt = 0; nt < 4; ++nt)
        acc[mt][nt] = __builtin_amdgcn_mfma_f32_16x16x32_bf16(fa[mt], fb[nt],
                                                              acc[mt][nt], 0, 0, 0);
    __syncthreads();
  }

  // dump gate tiles to LDS (C layout: row = quad*4+v, col = lane&15)
#pragma unroll
  for (int mt = 0; mt < 4; ++mt)
#pragma unroll
    for (int nt = 0; nt < 4; ++nt)
#pragma unroll
      for (int v = 0; v < 4; ++v)
        sh.gates[wave][(mt * 16 + quad * 4 + v) * 64 + nt * 16 + l16] =
            acc[mt][nt][v];
  __syncthreads();

  // cell update: 64 lanes cover one row; 4 rows per pass; 16 passes
  const int mrow = tid >> 6;
  const int n = tid & 63;
#pragma unroll 4
  for (int it = 0; it < 16; ++it) {
    int m = it * 4 + mrow;
    int b = bBase + m;
    int j = n0 + n;
    float gi = sigmoidf_(sh.gates[0][m * 64 + n]);
    float gf = sigmoidf_(sh.gates[1][m * 64 + n]);
    float gg = tanhf_  (sh.gates[2][m * 64 + n]);
    float go = sigmoidf_(sh.gates[3][m * 64 + n]);
    float cold = cbuf[(size_t)b * 1024 + j];
    float cn = gf * cold + gi * gg;
    float hn = go * tanhf_(cn);
    out[((size_t)b * 32 + t) * 1024 + j] = hn;           // x_out (pre-reset h)
    // fold NEXT step's reset into the carries; step t+1 reset = dones[b*32+t]
    float keep = (t < 31) ? (1.0f - dones[b * 32 + t]) : 1.0f;
    cbuf[(size_t)b * 1024 + j] = cn * keep;
    h_out[(size_t)b * 1024 + j] = f2bf(hn * keep);
    if (t == 31) {                                        // final states, un-reset
      rnn_out[(size_t)b * 2048 + j] = hn;
      rnn_out[(size_t)b * 2048 + 1024 + j] = cn;
    }
  }
}

// ---------------- launcher ----------------
extern "C" void kernel_launch(void* const* d_in, const int* in_sizes, int n_in,
                              void* d_out, int out_size, void* d_ws, size_t ws_size,
                              hipStream_t stream) {
  (void)in_sizes; (void)n_in; (void)out_size; (void)ws_size;
  const float* head  = (const float*)d_in[0];  // [65536][1024]
  const float* rnn   = (const float*)d_in[1];  // [2048][2048]
  const float* dones = (const float*)d_in[2];  // [65536]
  const float* wih   = (const float*)d_in[3];  // [4096][1024]
  const float* whh   = (const float*)d_in[4];  // [4096][1024]
  const float* bih   = (const float*)d_in[5];  // [4096]
  const float* bhh   = (const float*)d_in[6];  // [4096]
  float* out = (float*)d_out;
  float* rnn_out = out + (size_t)65536 * 1024;

  char* ws = (char*)d_ws;
  unsigned short* X    = (unsigned short*)(ws);                 // 128 MB
  unsigned short* Wcat = (unsigned short*)(ws + 134217728);     // 16 MB
  float*          bias = (float*)(ws + 150994944);              // 16 KB
  unsigned short* h0   = (unsigned short*)(ws + 151011328);     // 4 MB
  unsigned short* h1   = (unsigned short*)(ws + 155205632);     // 4 MB
  float*          cbuf = (float*)(ws + 159399936);              // 8 MB
  // total ws use: ~160 MB

  cvt_bf16_kernel<<<65536, 256, 0, stream>>>(head, X, 16777216);
  wcat_kernel<<<8192, 256, 0, stream>>>(wih, whh, Wcat);
  state_prep<<<8192, 256, 0, stream>>>(rnn, bih, bhh, h0, cbuf, bias);

  unsigned short* hb[2] = {h0, h1};
  for (int t = 0; t < TSTEP; ++t) {
    lstm_step<<<dim3(32, 16), 256, 0, stream>>>(
        X, Wcat, bias, dones, hb[t & 1], hb[(t + 1) & 1], cbuf, out, rnn_out, t);
  }
}